// Round 18
// baseline (126.717 us; speedup 1.0000x reference)
//
#include <hip/hip_runtime.h>

#define NUM_K 64
#define CDIM 32
#define HW 16384          // 128*128
#define NPTS 1048576      // 64*128*128
#define NELEMD 33554432.0 // 64*32*128*128

typedef float v2f __attribute__((ext_vector_type(2)));

// numpy pairwise sum of squares, n=32 contiguous: 8 accumulators + fixed tree.
__device__ __forceinline__ float np_sumsq32(const float* v) {
#pragma clang fp contract(off)
    float r[8];
    #pragma unroll
    for (int j = 0; j < 8; ++j) {
        float p0 = v[j] * v[j];
        float p1 = v[j + 8] * v[j + 8];
        float p2 = v[j + 16] * v[j + 16];
        float p3 = v[j + 24] * v[j + 24];
        r[j] = ((p0 + p1) + p2) + p3;
    }
    return ((r[0] + r[1]) + (r[2] + r[3])) + ((r[4] + r[5]) + (r[6] + r[7]));
}

__global__ void vq_prep(const float* __restrict__ emb, float* __restrict__ Bg,
                        float* __restrict__ embT) {
#pragma clang fp contract(off)
    int k = threadIdx.x;
    if (k < NUM_K) {
        float e[CDIM];
        #pragma unroll
        for (int c = 0; c < CDIM; ++c) e[c] = emb[k * CDIM + c];
        Bg[k] = np_sumsq32(e);
        #pragma unroll
        for (int c = 0; c < CDIM; ++c) embT[c * NUM_K + k] = e[c];
    }
}

// Half-k wave-pair split, UNCAPPED (the clean occupancy experiment):
// block = 256 threads = 128 points; waves {0,2} own k in [0,32), waves {1,3}
// own k in [32,64) for the same 64-point groups. Inner loop identical in kind
// to R10 (register x, s_load codebook rows, packed fma) but acc file halves
// to 16 v2f = 32 VGPRs -> total live ~60, naturally under the 64-reg tier.
// NO __launch_bounds__ min-waves: R11/R12's spills came from infeasible caps.
// x read twice per point (partner wave, same block -> L1/L2); stores split
// across the pair (R14's wave-0-only store phase was a measured defect).
__global__ __launch_bounds__(256) void vq_main(const float* __restrict__ x,
                                               const float* __restrict__ embT,
                                               const float* __restrict__ Bg,
                                               float* __restrict__ outq,
                                               double* __restrict__ ws) {
#pragma clang fp contract(off)
    __shared__ float sET[CDIM * NUM_K];  // gather table (embT layout [c][k])
    __shared__ float sBest[4][64];       // [wave][lane]
    __shared__ int   sBi[4][64];
    __shared__ float sRed[4];

    const int t = threadIdx.x;
    #pragma unroll
    for (int i = t; i < NUM_K * CDIM; i += 256)
        sET[i] = embT[i];                // coalesced read, conflict-free write

    const int w = t >> 6, l = t & 63;
    const int half = w & 1;              // k-half owned by this wave
    const int grp  = w >> 1;             // point-group 0/1
    // kbase wave-uniform; pin to SGPR so codebook rows stay s_load.
    const int kbase = __builtin_amdgcn_readfirstlane(half << 5);

    const int p = blockIdx.x * 128 + grp * 64 + l;   // 128 | HW: one image/block
    const int b = p >> 14;
    const size_t base = (size_t)b * (CDIM * HW) + (p & (HW - 1));
    const float* xp = x + base;

    v2f acc2[16];                        // k = kbase+2q, kbase+2q+1
    #pragma unroll
    for (int q = 0; q < 16; ++q) acc2[q] = (v2f){0.f, 0.f};
    float r[8];                          // numpy pairwise-tree partials for A

    #pragma unroll
    for (int g = 0; g < 4; ++g) {
        float xg[8];
        #pragma unroll
        for (int j = 0; j < 8; ++j)
            xg[j] = xp[(size_t)(g * 8 + j) * HW];    // coalesced across lanes
        #pragma unroll
        for (int j = 0; j < 8; ++j) {
            const int c = g * 8 + j;
            const float xc = xg[j];
            const float pp = xc * xc;                // rounds individually
            // r_j = ((p_j + p_{j+8}) + p_{j+16}) + p_{j+24} == numpy tree
            if (g == 0) r[j] = pp; else r[j] = r[j] + pp;
            const v2f xx = (v2f){xc, xc};
            const v2f* __restrict__ e2 = (const v2f*)(embT + c * NUM_K + kbase);
            #pragma unroll
            for (int q = 0; q < 16; ++q)
                acc2[q] = __builtin_elementwise_fma(xx, e2[q], acc2[q]);
        }
    }
    const float A = ((r[0] + r[1]) + (r[2] + r[3])) + ((r[4] + r[5]) + (r[6] + r[7]));

    // d_k = fmaf(-2, C_k, A+B_k) == fp32(fp32(A+B_k) - 2*C_k) bitwise; C_k is
    // the exact ascending-c fma chain of all passing rounds. Ascending k +
    // strict < => first-min within this wave's k-half.
    float best = 3.4028235e38f;
    int bi = 0;
    #pragma unroll
    for (int q = 0; q < 16; ++q) {
        int k0 = kbase + 2 * q;
        float d0 = fmaf(-2.f, acc2[q].x, A + Bg[k0]);
        float d1 = fmaf(-2.f, acc2[q].y, A + Bg[k0 + 1]);
        if (d0 < best) { best = d0; bi = k0; }
        if (d1 < best) { best = d1; bi = k0 + 1; }
    }
    sBest[w][l] = best;
    sBi[w][l] = bi;
    __syncthreads();   // also covers sET staging

    // Symmetric cross-half combine (both waves end with identical winner):
    // low half wins ties => global first-min (low half's k are all smaller).
    {
        float ob = sBest[w ^ 1][l];
        int obi = sBi[w ^ 1][l];
        if (half == 0) { if (ob < best)  { best = ob; bi = obi; } }
        else           { if (ob <= best) { best = ob; bi = obi; } }
    }

    // Store split across the pair: this wave stores channels [16*half, 16*half+16).
    float* op = outq + base;
    #pragma unroll
    for (int cc = 0; cc < 16; ++cc) {
        int c = (half << 4) + cc;
        op[(size_t)c * HW] = sET[c * NUM_K + bi];   // coalesced; bank=bi: ~free
    }

    // Loss: count each point once (low-half waves only). best == point's
    // squared distance (validated R9).
    float lsum = (half == 0) ? best : 0.f;
    #pragma unroll
    for (int off = 32; off > 0; off >>= 1)
        lsum += __shfl_down(lsum, off, 64);
    if (l == 0) sRed[w] = lsum;
    __syncthreads();
    if (t == 0) {
        double bs = (double)sRed[0] + (double)sRed[1] + (double)sRed[2] + (double)sRed[3];
        atomicAdd(ws, bs);
    }
}

__global__ void vq_finish(const double* __restrict__ ws, float* __restrict__ loss) {
    loss[0] = (float)(1.25 * ws[0] / NELEMD);
}

extern "C" void kernel_launch(void* const* d_in, const int* in_sizes, int n_in,
                              void* d_out, int out_size, void* d_ws, size_t ws_size,
                              hipStream_t stream) {
    const float* x = (const float*)d_in[0];
    const float* emb = (const float*)d_in[1];
    float* out = (float*)d_out;
    // ws layout: [0,8) double loss acc; [64,320) Bg[64]; [320,8512) embT[32][64]
    double* acc = (double*)d_ws;
    float* Bg = (float*)((char*)d_ws + 64);
    float* embT = (float*)((char*)d_ws + 320);

    hipMemsetAsync(d_ws, 0, sizeof(double), stream);
    vq_prep<<<1, 64, 0, stream>>>(emb, Bg, embT);
    vq_main<<<NPTS / 128, 256, 0, stream>>>(x, embT, Bg, out + 1, acc);
    vq_finish<<<1, 1, 0, stream>>>(acc, out);
}

// Round 19
// 93.477 us; speedup vs baseline: 1.3556x; 1.3556x over previous
//
#include <hip/hip_runtime.h>

#define NUM_K 64
#define CDIM 32
#define HW 16384          // 128*128
#define HW2 8192          // HW/2 in float2 units
#define NPTS 1048576      // 64*128*128
#define NELEMD 33554432.0 // 64*32*128*128

typedef float v2f __attribute__((ext_vector_type(2)));

// numpy pairwise sum of squares, n=32 contiguous: 8 accumulators + fixed tree.
__device__ __forceinline__ float np_sumsq32(const float* v) {
#pragma clang fp contract(off)
    float r[8];
    #pragma unroll
    for (int j = 0; j < 8; ++j) {
        float p0 = v[j] * v[j];
        float p1 = v[j + 8] * v[j + 8];
        float p2 = v[j + 16] * v[j + 16];
        float p3 = v[j + 24] * v[j + 24];
        r[j] = ((p0 + p1) + p2) + p3;
    }
    return ((r[0] + r[1]) + (r[2] + r[3])) + ((r[4] + r[5]) + (r[6] + r[7]));
}

__global__ void vq_prep(const float* __restrict__ emb, float* __restrict__ Bg,
                        float* __restrict__ embT) {
#pragma clang fp contract(off)
    int k = threadIdx.x;
    if (k < NUM_K) {
        float e[CDIM];
        #pragma unroll
        for (int c = 0; c < CDIM; ++c) e[c] = emb[k * CDIM + c];
        Bg[k] = np_sumsq32(e);
        #pragma unroll
        for (int c = 0; c < CDIM; ++c) embT[c * NUM_K + k] = e[c];
    }
}

// Point-PAIR per thread (v2f loads/stores: halves VMEM request count, the
// suspected limiter: R10=64 req/pt -> 85us; R18=96 req/pt -> 127us) x half-k
// per wave (keeps acc file at 64 regs so total live ~112 stays in R10's
// 4-waves/SIMD tier -- occupancy held constant, VMEM halved: clean test).
// Waves {0,2}: k in [0,32); {1,3}: k in [32,64) for the same 128-point groups.
__global__ __launch_bounds__(256) void vq_main(const float* __restrict__ x,
                                               const float* __restrict__ embT,
                                               const float* __restrict__ Bg,
                                               float* __restrict__ outq,
                                               double* __restrict__ ws) {
#pragma clang fp contract(off)
    __shared__ float sET[CDIM * NUM_K];  // gather table (embT layout [c][k])
    __shared__ float sBestA[4][64], sBestB[4][64];
    __shared__ int   sBiA[4][64],   sBiB[4][64];
    __shared__ float sRed[4];

    const int t = threadIdx.x;
    #pragma unroll
    for (int i = t; i < NUM_K * CDIM; i += 256)
        sET[i] = embT[i];                // coalesced read, conflict-free write

    const int w = t >> 6, l = t & 63;
    const int half = w & 1;              // k-half owned by this wave
    const int grp  = w >> 1;             // point-group 0/1 (128 pts each)
    const int kbase = __builtin_amdgcn_readfirstlane(half << 5);

    // This thread owns points p and p+1 (p even -> v2f aligned).
    const int p = blockIdx.x * 256 + grp * 128 + 2 * l;  // 256 | HW: one image/block
    const int b = p >> 14;
    const size_t base = (size_t)b * (CDIM * HW) + (p & (HW - 1));
    const v2f* xp2 = (const v2f*)(x + base);

    v2f accA[16], accB[16];              // per point: k = kbase+2q, +2q+1
    #pragma unroll
    for (int q = 0; q < 16; ++q) { accA[q] = (v2f){0.f, 0.f}; accB[q] = (v2f){0.f, 0.f}; }
    float rA[8], rB[8];                  // numpy pairwise-tree partials per point

    #pragma unroll
    for (int g = 0; g < 4; ++g) {
        v2f xg[8];
        #pragma unroll
        for (int j = 0; j < 8; ++j)
            xg[j] = xp2[(size_t)(g * 8 + j) * HW2];  // 512B coalesced wave-load
        #pragma unroll
        for (int j = 0; j < 8; ++j) {
            const int c = g * 8 + j;
            const float xa = xg[j].x, xb = xg[j].y;
            const float ppa = xa * xa, ppb = xb * xb;   // round individually
            // r_j = ((p_j + p_{j+8}) + p_{j+16}) + p_{j+24} == numpy tree
            if (g == 0) { rA[j] = ppa; rB[j] = ppb; }
            else        { rA[j] = rA[j] + ppa; rB[j] = rB[j] + ppb; }
            const v2f xxa = (v2f){xa, xa}, xxb = (v2f){xb, xb};
            const v2f* __restrict__ e2 = (const v2f*)(embT + c * NUM_K + kbase);
            #pragma unroll
            for (int q = 0; q < 16; ++q) {              // e2[q] shared by both pts
                accA[q] = __builtin_elementwise_fma(xxa, e2[q], accA[q]);
                accB[q] = __builtin_elementwise_fma(xxb, e2[q], accB[q]);
            }
        }
    }
    const float AA = ((rA[0] + rA[1]) + (rA[2] + rA[3])) + ((rA[4] + rA[5]) + (rA[6] + rA[7]));
    const float AB = ((rB[0] + rB[1]) + (rB[2] + rB[3])) + ((rB[4] + rB[5]) + (rB[6] + rB[7]));

    // d_k = fmaf(-2, C_k, A+B_k) == fp32(fp32(A+B_k) - 2*C_k) bitwise; C_k is
    // the exact ascending-c fma chain of all passing rounds. Ascending k +
    // strict < => first-min within this wave's k-half.
    float bestA = 3.4028235e38f, bestB = 3.4028235e38f;
    int biA = 0, biB = 0;
    #pragma unroll
    for (int q = 0; q < 16; ++q) {
        int k0 = kbase + 2 * q;
        float bk0 = Bg[k0], bk1 = Bg[k0 + 1];
        float dA0 = fmaf(-2.f, accA[q].x, AA + bk0);
        float dA1 = fmaf(-2.f, accA[q].y, AA + bk1);
        float dB0 = fmaf(-2.f, accB[q].x, AB + bk0);
        float dB1 = fmaf(-2.f, accB[q].y, AB + bk1);
        if (dA0 < bestA) { bestA = dA0; biA = k0; }
        if (dA1 < bestA) { bestA = dA1; biA = k0 + 1; }
        if (dB0 < bestB) { bestB = dB0; biB = k0; }
        if (dB1 < bestB) { bestB = dB1; biB = k0 + 1; }
    }
    sBestA[w][l] = bestA; sBiA[w][l] = biA;
    sBestB[w][l] = bestB; sBiB[w][l] = biB;
    __syncthreads();   // also covers sET staging

    // Symmetric cross-half combine; low half wins ties => global first-min.
    {
        float oA = sBestA[w ^ 1][l]; int oiA = sBiA[w ^ 1][l];
        float oB = sBestB[w ^ 1][l]; int oiB = sBiB[w ^ 1][l];
        if (half == 0) {
            if (oA < bestA)  { bestA = oA; biA = oiA; }
            if (oB < bestB)  { bestB = oB; biB = oiB; }
        } else {
            if (oA <= bestA) { bestA = oA; biA = oiA; }
            if (oB <= bestB) { bestB = oB; biB = oiB; }
        }
    }

    // Store split across the pair: this wave stores channels [16*half, +16)
    // for both its points, as 512B coalesced v2f wave-stores.
    v2f* op2 = (v2f*)(outq + base);
    #pragma unroll
    for (int cc = 0; cc < 16; ++cc) {
        int c = (half << 4) + cc;
        v2f qv;
        qv.x = sET[c * NUM_K + biA];     // bank=bi: random, ~free
        qv.y = sET[c * NUM_K + biB];
        op2[(size_t)c * HW2] = qv;
    }

    // Loss: count each point once (low-half waves only); best == sq distance.
    float lsum = (half == 0) ? (bestA + bestB) : 0.f;
    #pragma unroll
    for (int off = 32; off > 0; off >>= 1)
        lsum += __shfl_down(lsum, off, 64);
    if (l == 0) sRed[w] = lsum;
    __syncthreads();
    if (t == 0) {
        double bs = (double)sRed[0] + (double)sRed[1] + (double)sRed[2] + (double)sRed[3];
        atomicAdd(ws, bs);
    }
}

__global__ void vq_finish(const double* __restrict__ ws, float* __restrict__ loss) {
    loss[0] = (float)(1.25 * ws[0] / NELEMD);
}

extern "C" void kernel_launch(void* const* d_in, const int* in_sizes, int n_in,
                              void* d_out, int out_size, void* d_ws, size_t ws_size,
                              hipStream_t stream) {
    const float* x = (const float*)d_in[0];
    const float* emb = (const float*)d_in[1];
    float* out = (float*)d_out;
    // ws layout: [0,8) double loss acc; [64,320) Bg[64]; [320,8512) embT[32][64]
    double* acc = (double*)d_ws;
    float* Bg = (float*)((char*)d_ws + 64);
    float* embT = (float*)((char*)d_ws + 320);

    hipMemsetAsync(d_ws, 0, sizeof(double), stream);
    vq_prep<<<1, 64, 0, stream>>>(emb, Bg, embT);
    vq_main<<<NPTS / 256, 256, 0, stream>>>(x, embT, Bg, out + 1, acc);
    vq_finish<<<1, 1, 0, stream>>>(acc, out);
}

// Round 20
// 84.693 us; speedup vs baseline: 1.4962x; 1.1037x over previous
//
#include <hip/hip_runtime.h>

#define NUM_K 64
#define CDIM 32
#define HW 16384          // 128*128
#define NPTS 1048576      // 64*128*128
#define NELEMD 33554432.0 // 64*32*128*128

typedef float v2f __attribute__((ext_vector_type(2)));

// numpy pairwise sum of squares, n=32 contiguous: 8 accumulators + fixed tree.
__device__ __forceinline__ float np_sumsq32(const float* v) {
#pragma clang fp contract(off)
    float r[8];
    #pragma unroll
    for (int j = 0; j < 8; ++j) {
        float p0 = v[j] * v[j];
        float p1 = v[j + 8] * v[j + 8];
        float p2 = v[j + 16] * v[j + 16];
        float p3 = v[j + 24] * v[j + 24];
        r[j] = ((p0 + p1) + p2) + p3;
    }
    return ((r[0] + r[1]) + (r[2] + r[3])) + ((r[4] + r[5]) + (r[6] + r[7]));
}

// Prep: B[k] = np.sum(emb*emb,axis=1) (numpy fp32 order) and embT[c][k]
// (transposed codebook, contiguous in k) -> global scratch.
__global__ void vq_prep(const float* __restrict__ emb, float* __restrict__ Bg,
                        float* __restrict__ embT) {
#pragma clang fp contract(off)
    int k = threadIdx.x;
    if (k < NUM_K) {
        float e[CDIM];
        #pragma unroll
        for (int c = 0; c < CDIM; ++c) e[c] = emb[k * CDIM + c];
        Bg[k] = np_sumsq32(e);
        #pragma unroll
        for (int c = 0; c < CDIM; ++c) embT[c * NUM_K + k] = e[c];
    }
}

// Loop-interchanged main (c outer, k inner) + 2-stage software pipeline.
// Session's measured optimum (R10: 84.8 us; reproduced R16: 86.0 us).
// Falsified alternatives: k-outer serial chains (R3-R8: remat/AGPR-parking),
// occupancy via k-splits (R11/R12/R14: spill or slower), clean half-k split
// (R18: +48%), MFMA screen (R15: 3x), v2f point-pairs (R19: +9%).
// Residual limiter (diagnosed, not fixable at HIP level): out-of-order SMEM
// returns force a full lgkmcnt drain per c-step row load -> ~35% VALU busy.
__global__ __launch_bounds__(256) void vq_main(const float* __restrict__ x,
                                               const float* __restrict__ embT,
                                               const float* __restrict__ Bg,
                                               float* __restrict__ outq,
                                               double* __restrict__ ws) {
#pragma clang fp contract(off)
    __shared__ float sET[CDIM][NUM_K];  // gather table (same layout as embT)
    __shared__ float sRed[4];

    const int t = threadIdx.x;
    #pragma unroll
    for (int i = t; i < NUM_K * CDIM; i += 256)
        ((float*)sET)[i] = embT[i];     // coalesced read, conflict-free write
    __syncthreads();

    const int p = blockIdx.x * 256 + t;
    const int b = p >> 14;
    const size_t base = (size_t)b * (CDIM * HW) + (p & (HW - 1));
    const float* xp = x + base;

    v2f acc2[CDIM];                     // acc2[q] = {C_{2q}, C_{2q+1}}
    #pragma unroll
    for (int q = 0; q < CDIM; ++q) acc2[q] = (v2f){0.f, 0.f};
    float r[8];                         // numpy pairwise-tree partials for A

    float cur[8], nxt[8];
    #pragma unroll
    for (int j = 0; j < 8; ++j)
        cur[j] = xp[(size_t)j * HW];    // prologue: group 0 loads

    #pragma unroll
    for (int g = 0; g < 4; ++g) {
        if (g < 3) {                    // issue next group's loads FIRST
            #pragma unroll
            for (int j = 0; j < 8; ++j)
                nxt[j] = xp[(size_t)((g + 1) * 8 + j) * HW];
        }
        #pragma unroll
        for (int j = 0; j < 8; ++j) {
            const int c = g * 8 + j;
            const float xc = cur[j];
            const float pp = xc * xc;               // rounds individually
            // r_j = ((p_j + p_{j+8}) + p_{j+16}) + p_{j+24}  == numpy tree
            if (g == 0) r[j] = pp; else r[j] = r[j] + pp;
            const v2f xx = (v2f){xc, xc};
            const v2f* __restrict__ e2 = (const v2f*)(embT + c * NUM_K); // uniform row
            #pragma unroll
            for (int q = 0; q < CDIM; ++q)
                acc2[q] = __builtin_elementwise_fma(xx, e2[q], acc2[q]); // per-elem fma
        }
        if (g < 3) {
            #pragma unroll
            for (int j = 0; j < 8; ++j) cur[j] = nxt[j];   // register rotate
        }
    }
    const float A = ((r[0] + r[1]) + (r[2] + r[3])) + ((r[4] + r[5]) + (r[6] + r[7]));

    // d_k = fp32( fp32(A + B_k) - 2*C_k ) == fmaf(-2, C_k, A+B_k) bitwise.
    // Ascending k, strict <  => first-min (np.argmin). Each C_k saw the exact
    // ascending-c fp32 fma chain of the passing R3/R4/R9 kernels.
    float best = 3.4028235e38f;
    int bi = 0;
    #pragma unroll
    for (int q = 0; q < CDIM; ++q) {
        float d0 = fmaf(-2.f, acc2[q].x, A + Bg[2 * q]);
        float d1 = fmaf(-2.f, acc2[q].y, A + Bg[2 * q + 1]);
        if (d0 < best) { best = d0; bi = 2 * q; }
        if (d1 < best) { best = d1; bi = 2 * q + 1; }
    }

    // Winner gather + coalesced stores. Loss contribution == best (validated R9).
    float* op = outq + base;
    #pragma unroll
    for (int c = 0; c < CDIM; ++c)
        op[(size_t)c * HW] = sET[c][bi];   // bank=bi%32 gather: ~free

    float lsum = best;
    #pragma unroll
    for (int off = 32; off > 0; off >>= 1)
        lsum += __shfl_down(lsum, off, 64);
    const int wid = t >> 6;
    if ((t & 63) == 0) sRed[wid] = lsum;
    __syncthreads();
    if (t == 0) {
        double bs = (double)sRed[0] + (double)sRed[1] + (double)sRed[2] + (double)sRed[3];
        atomicAdd(ws, bs);
    }
}

__global__ void vq_finish(const double* __restrict__ ws, float* __restrict__ loss) {
    loss[0] = (float)(1.25 * ws[0] / NELEMD);
}

extern "C" void kernel_launch(void* const* d_in, const int* in_sizes, int n_in,
                              void* d_out, int out_size, void* d_ws, size_t ws_size,
                              hipStream_t stream) {
    const float* x = (const float*)d_in[0];
    const float* emb = (const float*)d_in[1];
    float* out = (float*)d_out;
    // ws layout: [0,8) double loss acc; [64,320) Bg[64]; [320,8512) embT[32][64]
    double* acc = (double*)d_ws;
    float* Bg = (float*)((char*)d_ws + 64);
    float* embT = (float*)((char*)d_ws + 320);

    hipMemsetAsync(d_ws, 0, sizeof(double), stream);
    vq_prep<<<1, 64, 0, stream>>>(emb, Bg, embT);
    vq_main<<<NPTS / 256, 256, 0, stream>>>(x, embT, Bg, out + 1, acc);
    vq_finish<<<1, 1, 0, stream>>>(acc, out);
}